// Round 6
// baseline (128.094 us; speedup 1.0000x reference)
//
#include <hip/hip_runtime.h>
#include <hip/hip_bf16.h>
#include <math.h>

// Problem: B=2, N=8192, M=8192, C=3, k=20; MLP 20->256->128->1 with BN+ReLU, sigmoid.
// Pipeline (3 launches):
//   k_prep : y -> pair-packed planes A=(y0a,y0b,y1a,y1b), B=(y2a,y2b,-wa,-wb)
//            + W2 transpose.
//   k_knn  : 4 query rows PER WAVE (amortizes candidate stream 4x: L2 traffic
//            2.1GB -> 536MB, compute covers load latency). Packed-f32 distance
//            (2 cand / 4 instrs), per-lane sorted top-4 (3 med3 + 1 max),
//            20-round cross-lane max-merge per query; exactness guard (lane
//            pops all 4 slots -> per-query exact redo with 20-deep chain).
//   k_mlp  : fused MLP, 32 rows/block, h1 in LDS (33 KB). W2T read from
//            global (L1-hot) - no LDS staging; both 64-out halves per kq
//            (64 fma / 10 loads). bn2+relu+W3 dot in-wave; sigmoid.

#define M_CAND 8192
#define NROWS 16384
#define KSEL 20
#define MPL 4            // per-lane list length (main path)
#define RPW 4            // query rows per wave

typedef float v2f __attribute__((ext_vector_type(2)));

__device__ __forceinline__ float med3f(float a, float b, float c) {
    return __builtin_amdgcn_fmed3f(a, b, c);
}

__device__ __forceinline__ v2f fma2(v2f a, v2f b, v2f c) {
#if __has_builtin(__builtin_elementwise_fma)
    return __builtin_elementwise_fma(a, b, c);
#else
    v2f r; r.x = fmaf(a.x, b.x, c.x); r.y = fmaf(a.y, b.y, c.y); return r;
#endif
}

// ---------- kernel: prep (y pair-pack + W2 transpose) ----------
__global__ __launch_bounds__(256) void k_prep(const float* __restrict__ y,
                                              const float* __restrict__ w2,
                                              float4* __restrict__ ysp,
                                              float* __restrict__ w2t) {
    int idx = blockIdx.x * 256 + threadIdx.x;     // 40960 total
    if (idx < 8192) {                             // 8192 candidate-pairs
        int b = idx >> 12, q = idx & 4095;
        const float* p0 = y + (size_t)(b * M_CAND + 2 * q) * 3;
        float a0 = p0[0], a1 = p0[1], a2 = p0[2];
        float b0 = p0[3], b1 = p0[4], b2 = p0[5];
        float nwa = -(a0 * a0 + a1 * a1 + a2 * a2);
        float nwb = -(b0 * b0 + b1 * b1 + b2 * b2);
        float4* base = ysp + b * 8192;
        base[q]        = make_float4(a0, b0, a1, b1);   // plane A
        base[4096 + q] = make_float4(a2, b2, nwa, nwb); // plane B
    } else {
        int j = idx - 8192;                       // 32768 W2 elements
        int o = j >> 8, kk = j & 255;
        w2t[kk * 128 + o] = w2[j];
    }
}

// ---------- kernel: kNN top-20 by pd (4 queries per wave) ----------
__global__ __launch_bounds__(256, 4) void k_knn(const float* __restrict__ x,
                                                const float4* __restrict__ ysp,
                                                float* __restrict__ dfeat) {
    __shared__ float sm[4][64 * 21];              // per-wave region, stride 5 / 21
    const int wid  = threadIdx.x >> 6;
    const int lane = threadIdx.x & 63;
    const int qbase = (blockIdx.x * 4 + wid) * RPW;   // grid 1024 -> 16384 rows
    const int b = qbase >> 13;                    // all RPW rows in same batch

    float tx0[RPW], tx1[RPW], tx2[RPW], xxn[RPW];
#pragma unroll
    for (int r = 0; r < RPW; ++r) {
        float a0 = x[(qbase + r) * 3 + 0];
        float a1 = x[(qbase + r) * 3 + 1];
        float a2 = x[(qbase + r) * 3 + 2];
        tx0[r] = 2.0f * a0; tx1[r] = 2.0f * a1; tx2[r] = 2.0f * a2;
        xxn[r] = -(a0 * a0 + a1 * a1 + a2 * a2);
    }
    const float4* pa = ysp + b * 8192 + lane;     // plane A; plane B at +4096
    const float4* pb = pa + 4096;

    // descending per-lane top-4 of pd per query
    float bl[RPW][MPL];
#pragma unroll
    for (int r = 0; r < RPW; ++r)
#pragma unroll
        for (int j = 0; j < MPL; ++j) bl[r][j] = -3.0e38f;

#define PROCESS_PAIR(Aq, Bq)                                                   \
    {                                                                          \
        v2f y0p = {(Aq).x, (Aq).y};                                            \
        v2f y1p = {(Aq).z, (Aq).w};                                            \
        v2f y2p = {(Bq).x, (Bq).y};                                            \
        v2f nwp = {(Bq).z, (Bq).w};                                            \
        _Pragma("unroll")                                                      \
        for (int r = 0; r < RPW; ++r) {                                        \
            v2f t0 = {tx0[r], tx0[r]};                                         \
            v2f t1 = {tx1[r], tx1[r]};                                         \
            v2f t2 = {tx2[r], tx2[r]};                                         \
            v2f xp = {xxn[r], xxn[r]};                                         \
            v2f pd = fma2(t0, y0p, fma2(t1, y1p, fma2(t2, y2p, xp))) + nwp;    \
            float va = pd.x, vb = pd.y;                                        \
            bl[r][3] = med3f(va, bl[r][2], bl[r][3]);                          \
            bl[r][2] = med3f(va, bl[r][1], bl[r][2]);                          \
            bl[r][1] = med3f(va, bl[r][0], bl[r][1]);                          \
            bl[r][0] = fmaxf(bl[r][0], va);                                    \
            bl[r][3] = med3f(vb, bl[r][2], bl[r][3]);                          \
            bl[r][2] = med3f(vb, bl[r][1], bl[r][2]);                          \
            bl[r][1] = med3f(vb, bl[r][0], bl[r][1]);                          \
            bl[r][0] = fmaxf(bl[r][0], vb);                                    \
        }                                                                      \
    }

    // main loop: 32 iters x 2 pair-quads x 64 lanes = 8192 candidates
    float4 A0 = pa[0], A1 = pa[64], B0 = pb[0], B1 = pb[64];
#pragma unroll 1
    for (int t = 0; t < 32; ++t) {
        const int nt = ((t + 1) & 31) * 128;
        float4 nA0 = pa[nt], nA1 = pa[nt + 64];
        float4 nB0 = pb[nt], nB1 = pb[nt + 64];
        PROCESS_PAIR(A0, B0)
        PROCESS_PAIR(A1, B1)
        A0 = nA0; A1 = nA1; B0 = nB0; B1 = nB1;
    }

    // per-query cross-lane merge: 20 rounds of wave-max over sorted heads
    float* myp = sm[wid] + lane * (MPL + 1);      // stride 5: conflict-free
    unsigned needmask = 0;
#pragma unroll
    for (int q = 0; q < RPW; ++q) {
#pragma unroll
        for (int j = 0; j < MPL; ++j) myp[j] = bl[q][j];
        myp[MPL] = -3.0e38f;                      // pad slot
        asm volatile("s_waitcnt lgkmcnt(0)" ::: "memory");
        int ptr = 0;
        float sel = 0.0f;
        for (int r = 0; r < KSEL; ++r) {
            float head = myp[ptr];
            float mx = head;
#pragma unroll
            for (int off = 32; off >= 1; off >>= 1) mx = fmaxf(mx, __shfl_xor(mx, off, 64));
            unsigned long long ball = __ballot(head == mx);
            int winner = (int)__ffsll(ball) - 1;  // first lane holding max (tie-safe)
            ptr += (lane == winner) ? 1 : 0;
            if (lane == r) sel = mx;
        }
        if (__ballot(ptr >= MPL) != 0ULL) needmask |= (1u << q);
        if (lane < KSEL) dfeat[(size_t)(qbase + q) * KSEL + lane] = sel;
    }

    // exactness fallback: per flagged query, full per-lane top-20 rescan
    if (needmask != 0) {
#pragma unroll
        for (int q = 0; q < RPW; ++q) {
            if (!(needmask & (1u << q))) continue;
            float a[KSEL];
#pragma unroll
            for (int j = 0; j < KSEL; ++j) a[j] = -3.0e38f;
#pragma unroll 1
            for (int t = 0; t < 32; ++t) {
                float4 dA0 = pa[t * 128], dA1 = pa[t * 128 + 64];
                float4 dB0 = pb[t * 128], dB1 = pb[t * 128 + 64];
                v2f t0 = {tx0[q], tx0[q]};
                v2f t1 = {tx1[q], tx1[q]};
                v2f t2 = {tx2[q], tx2[q]};
                v2f xp = {xxn[q], xxn[q]};
                v2f pd0 = fma2(t0, (v2f){dA0.x, dA0.y},
                          fma2(t1, (v2f){dA0.z, dA0.w},
                          fma2(t2, (v2f){dB0.x, dB0.y}, xp))) + (v2f){dB0.z, dB0.w};
                v2f pd1 = fma2(t0, (v2f){dA1.x, dA1.y},
                          fma2(t1, (v2f){dA1.z, dA1.w},
                          fma2(t2, (v2f){dB1.x, dB1.y}, xp))) + (v2f){dB1.z, dB1.w};
                float vv[4] = {pd0.x, pd0.y, pd1.x, pd1.y};
#pragma unroll
                for (int i = 0; i < 4; ++i) {
                    float v = vv[i];
#pragma unroll
                    for (int jj = KSEL - 1; jj >= 1; --jj) a[jj] = med3f(v, a[jj - 1], a[jj]);
                    a[0] = fmaxf(a[0], v);
                }
            }
            float* mq = sm[wid] + lane * (KSEL + 1);  // stride 21
#pragma unroll
            for (int j = 0; j < KSEL; ++j) mq[j] = a[j];
            mq[KSEL] = -3.0e38f;
            asm volatile("s_waitcnt lgkmcnt(0)" ::: "memory");
            int ptr2 = 0;
            float sel2 = 0.0f;
            for (int r = 0; r < KSEL; ++r) {
                float head = mq[ptr2];
                float mx = head;
#pragma unroll
                for (int off = 32; off >= 1; off >>= 1) mx = fmaxf(mx, __shfl_xor(mx, off, 64));
                unsigned long long ball = __ballot(head == mx);
                int winner = (int)__ffsll(ball) - 1;
                ptr2 += (lane == winner) ? 1 : 0;
                if (lane == r) sel2 = mx;
            }
            if (lane < KSEL) dfeat[(size_t)(qbase + q) * KSEL + lane] = sel2;
        }
    }
#undef PROCESS_PAIR
}

// ---------- kernel: fused MLP (bn1/relu -> GEMM2 -> bn2/relu -> W3 -> sigmoid) ----------
__global__ __launch_bounds__(256) void k_mlp(const float* __restrict__ dfeat,
                                             const float* __restrict__ W1,
                                             const float* __restrict__ g1,
                                             const float* __restrict__ be1,
                                             const float* __restrict__ mu1,
                                             const float* __restrict__ va1,
                                             const float* __restrict__ W2T,
                                             const float* __restrict__ g2,
                                             const float* __restrict__ be2,
                                             const float* __restrict__ mu2,
                                             const float* __restrict__ va2,
                                             const float* __restrict__ W3,
                                             float* __restrict__ out) {
    __shared__ float h1l[32 * 260];               // 33,280 B (stride 260: conflict-free)
    const int t = threadIdx.x;
    const int rowbase = blockIdx.x * 32;          // grid 512 -> all 16384 rows

    // phase-1 per-thread weights (o = t)
    float w[KSEL];
#pragma unroll
    for (int j = 0; j < KSEL; j += 4) {
        float4 q = *(const float4*)(W1 + t * KSEL + j);
        w[j] = q.x; w[j + 1] = q.y; w[j + 2] = q.z; w[j + 3] = q.w;
    }
    const float s1  = g1[t] * rsqrtf(va1[t] + 1e-5f);
    const float bc1 = be1[t] - mu1[t] * s1;

    // phase 1: h1[r][o] = relu(bn1(W1 . feat)), o = t; feat read from global
    // (wave-uniform broadcast loads, L1/L2-hot)
    for (int r = 0; r < 32; ++r) {
        const float* dr = dfeat + (size_t)(rowbase + r) * KSEL;
        float dv[KSEL];
#pragma unroll
        for (int j = 0; j < KSEL; j += 4) {
            float4 q = *(const float4*)(dr + j);
            dv[j] = q.x; dv[j + 1] = q.y; dv[j + 2] = q.z; dv[j + 3] = q.w;
        }
        float acc0 = 0.f, acc1 = 0.f;
#pragma unroll
        for (int j = 0; j < KSEL; j += 2) {
            acc0 = fmaf(w[j], dv[j], acc0);
            acc1 = fmaf(w[j + 1], dv[j + 1], acc1);
        }
        h1l[r * 260 + t] = fmaxf(0.f, fmaf(s1, acc0 + acc1, bc1));
    }
    __syncthreads();                              // h1l ready

    // phase 2: GEMM 32 rows x 128 outs; thread = (og, rq): outs og*4+i in each
    // 64-half, rows rq*2+rr. W2T from global (L1-hot), h1 from LDS.
    const int og = t & 15;
    const int rq = t >> 4;
    float acc[2][8];                              // [row][half*4+i]
#pragma unroll
    for (int r = 0; r < 2; ++r)
#pragma unroll
        for (int i = 0; i < 8; ++i) acc[r][i] = 0.f;

    for (int kq = 0; kq < 64; ++kq) {
        const int k = kq * 4;
        float4 hq[2];
#pragma unroll
        for (int rr = 0; rr < 2; ++rr)
            hq[rr] = *(const float4*)(&h1l[(rq * 2 + rr) * 260 + k]);
        float4 wq[8];                             // [kk] half0, [4+kk] half1
#pragma unroll
        for (int kk = 0; kk < 4; ++kk) {
            wq[kk]     = *(const float4*)(W2T + (k + kk) * 128 + og * 4);
            wq[4 + kk] = *(const float4*)(W2T + (k + kk) * 128 + 64 + og * 4);
        }
#pragma unroll
        for (int r = 0; r < 2; ++r) {
            const float* hh = (const float*)&hq[r];
#pragma unroll
            for (int kk = 0; kk < 4; ++kk) {
                const float hval = hh[kk];
                const float* w0 = (const float*)&wq[kk];
                const float* w1 = (const float*)&wq[4 + kk];
#pragma unroll
                for (int i = 0; i < 4; ++i) {
                    acc[r][i]     = fmaf(hval, w0[i], acc[r][i]);
                    acc[r][4 + i] = fmaf(hval, w1[i], acc[r][4 + i]);
                }
            }
        }
    }

    // epilogue: bn2 + relu + W3 weighting over 8 owned outs, reduce over og
    float s2v[8], b2v[8], w3v[8];
#pragma unroll
    for (int h = 0; h < 2; ++h)
#pragma unroll
        for (int i = 0; i < 4; ++i) {
            const int o = h * 64 + og * 4 + i;
            const float sv = g2[o] * rsqrtf(va2[o] + 1e-5f);
            s2v[h * 4 + i] = sv;
            b2v[h * 4 + i] = be2[o] - mu2[o] * sv;
            w3v[h * 4 + i] = W3[o];
        }
#pragma unroll
    for (int r = 0; r < 2; ++r) {
        float c = 0.f;
#pragma unroll
        for (int i = 0; i < 8; ++i) {
            float h2 = fmaxf(0.f, fmaf(s2v[i], acc[r][i], b2v[i]));
            c = fmaf(w3v[i], h2, c);
        }
#pragma unroll
        for (int off = 8; off >= 1; off >>= 1) c += __shfl_xor(c, off, 64);
        if (og == 0) {
            float z = c;
            out[rowbase + rq * 2 + r] = 1.0f / (1.0f + expf(-z));
        }
    }
}

extern "C" void kernel_launch(void* const* d_in, const int* in_sizes, int n_in,
                              void* d_out, int out_size, void* d_ws, size_t ws_size,
                              hipStream_t stream) {
    const float* x   = (const float*)d_in[0];
    const float* y   = (const float*)d_in[1];
    const float* W1  = (const float*)d_in[2];
    const float* g1  = (const float*)d_in[3];
    const float* be1 = (const float*)d_in[4];
    const float* mu1 = (const float*)d_in[5];
    const float* va1 = (const float*)d_in[6];
    const float* W2  = (const float*)d_in[7];
    const float* g2  = (const float*)d_in[8];
    const float* be2 = (const float*)d_in[9];
    const float* mu2 = (const float*)d_in[10];
    const float* va2 = (const float*)d_in[11];
    const float* W3  = (const float*)d_in[12];
    float* out = (float*)d_out;

    char* ws = (char*)d_ws;
    float4* ysp  = (float4*)(ws);                                   // 262,144 B
    float* dfeat = (float*)(ws + 262144);                           // 1,310,720 B
    float* w2t   = (float*)(ws + 262144 + 1310720);                 // 131,072 B

    k_prep<<<160, 256, 0, stream>>>(y, W2, ysp, w2t);
    k_knn <<<1024, 256, 0, stream>>>(x, ysp, dfeat);
    k_mlp <<<512, 256, 0, stream>>>(dfeat, W1, g1, be1, mu1, va1,
                                    w2t, g2, be2, mu2, va2, W3, out);
}

// Round 7
// 126.995 us; speedup vs baseline: 1.0086x; 1.0086x over previous
//
#include <hip/hip_runtime.h>
#include <hip/hip_bf16.h>
#include <math.h>

// Problem: B=2, N=8192, M=8192, C=3, k=20; MLP 20->256->128->1 with BN+ReLU, sigmoid.
// Pipeline (3 launches):
//   k_prep : y -> pair-packed planes A=(y0a,y0b,y1a,y1b), B=(y2a,y2b,-wa,-wb)
//            + W2 transpose.
//   k_knn  : 4 queries/wave, 16 queries/block. Candidates staged per-block
//            into LDS in 8KB tiles (reg-staged, T14 issue-early/write-late),
//            all 4 waves consume from LDS (ds_read_b128, conflict-free).
//            Packed-f32 distance, per-lane sorted top-4 (3 med3 + 1 max),
//            REGISTER-ONLY 20-round cross-lane merge (winner lane shifts its
//            4-deep list; no LDS in the dependence chain). Exactness guard:
//            lane pops all 4 slots -> per-query exact redo (20-deep, global).
//   k_mlp  : fused MLP, 32 rows/block, h1 in LDS. W2T read from global
//            (L2-hot). bn2+relu+W3 dot in-wave; sigmoid.

#define M_CAND 8192
#define NROWS 16384
#define KSEL 20
#define MPL 4            // per-lane list length (main path)
#define RPW 4            // query rows per wave
#define TPAIRS 256       // candidate pairs per LDS tile (8KB)
#define NTILES 16        // 16 tiles x 256 pairs x 2 = 8192 candidates

typedef float v2f __attribute__((ext_vector_type(2)));

__device__ __forceinline__ float med3f(float a, float b, float c) {
    return __builtin_amdgcn_fmed3f(a, b, c);
}

__device__ __forceinline__ v2f fma2(v2f a, v2f b, v2f c) {
#if __has_builtin(__builtin_elementwise_fma)
    return __builtin_elementwise_fma(a, b, c);
#else
    v2f r; r.x = fmaf(a.x, b.x, c.x); r.y = fmaf(a.y, b.y, c.y); return r;
#endif
}

// ---------- kernel: prep (y pair-pack + W2 transpose) ----------
__global__ __launch_bounds__(256) void k_prep(const float* __restrict__ y,
                                              const float* __restrict__ w2,
                                              float4* __restrict__ ysp,
                                              float* __restrict__ w2t) {
    int idx = blockIdx.x * 256 + threadIdx.x;     // 40960 total
    if (idx < 8192) {                             // 8192 candidate-pairs
        int b = idx >> 12, q = idx & 4095;
        const float* p0 = y + (size_t)(b * M_CAND + 2 * q) * 3;
        float a0 = p0[0], a1 = p0[1], a2 = p0[2];
        float b0 = p0[3], b1 = p0[4], b2 = p0[5];
        float nwa = -(a0 * a0 + a1 * a1 + a2 * a2);
        float nwb = -(b0 * b0 + b1 * b1 + b2 * b2);
        float4* base = ysp + b * 8192;
        base[q]        = make_float4(a0, b0, a1, b1);   // plane A
        base[4096 + q] = make_float4(a2, b2, nwa, nwb); // plane B
    } else {
        int j = idx - 8192;                       // 32768 W2 elements
        int o = j >> 8, kk = j & 255;
        w2t[kk * 128 + o] = w2[j];
    }
}

// ---------- kernel: kNN top-20 by pd (4 queries/wave, LDS-tiled candidates) ----------
__global__ __launch_bounds__(256, 4) void k_knn(const float* __restrict__ x,
                                                const float4* __restrict__ ysp,
                                                float* __restrict__ dfeat) {
    __shared__ float4 tileA[TPAIRS];              // 4KB
    __shared__ float4 tileB[TPAIRS];              // 4KB
    const int tid  = threadIdx.x;
    const int wid  = tid >> 6;
    const int lane = tid & 63;
    const int qbase = (blockIdx.x * 4 + wid) * RPW;   // grid 1024 -> 16384 rows
    const int b = qbase >> 13;                    // whole block is in one batch

    float tx0[RPW], tx1[RPW], tx2[RPW], xxn[RPW];
#pragma unroll
    for (int r = 0; r < RPW; ++r) {
        float a0 = x[(qbase + r) * 3 + 0];
        float a1 = x[(qbase + r) * 3 + 1];
        float a2 = x[(qbase + r) * 3 + 2];
        tx0[r] = 2.0f * a0; tx1[r] = 2.0f * a1; tx2[r] = 2.0f * a2;
        xxn[r] = -(a0 * a0 + a1 * a1 + a2 * a2);
    }
    const float4* ybA = ysp + b * 8192;           // plane A base
    const float4* ybB = ybA + 4096;               // plane B base

    // descending per-lane top-4 of pd per query
    float bl[RPW][MPL];
#pragma unroll
    for (int r = 0; r < RPW; ++r)
#pragma unroll
        for (int j = 0; j < MPL; ++j) bl[r][j] = -3.0e38f;

#define PROCESS_PAIR(Aq, Bq)                                                   \
    {                                                                          \
        v2f y0p = {(Aq).x, (Aq).y};                                            \
        v2f y1p = {(Aq).z, (Aq).w};                                            \
        v2f y2p = {(Bq).x, (Bq).y};                                            \
        v2f nwp = {(Bq).z, (Bq).w};                                            \
        _Pragma("unroll")                                                      \
        for (int r = 0; r < RPW; ++r) {                                        \
            v2f t0 = {tx0[r], tx0[r]};                                         \
            v2f t1 = {tx1[r], tx1[r]};                                         \
            v2f t2 = {tx2[r], tx2[r]};                                         \
            v2f xp = {xxn[r], xxn[r]};                                         \
            v2f pd = fma2(t0, y0p, fma2(t1, y1p, fma2(t2, y2p, xp))) + nwp;    \
            float va = pd.x, vb = pd.y;                                        \
            bl[r][3] = med3f(va, bl[r][2], bl[r][3]);                          \
            bl[r][2] = med3f(va, bl[r][1], bl[r][2]);                          \
            bl[r][1] = med3f(va, bl[r][0], bl[r][1]);                          \
            bl[r][0] = fmaxf(bl[r][0], va);                                    \
            bl[r][3] = med3f(vb, bl[r][2], bl[r][3]);                          \
            bl[r][2] = med3f(vb, bl[r][1], bl[r][2]);                          \
            bl[r][1] = med3f(vb, bl[r][0], bl[r][1]);                          \
            bl[r][0] = fmaxf(bl[r][0], vb);                                    \
        }                                                                      \
    }

    // main loop over 16 tiles: reg-stage next tile while computing current.
    // Per tile: 256 threads write 256 A + 256 B float4 (1 each); per wave
    // 4 pair-iters x (2 ds_read_b128 + 48 VALU).
    float4 rA = ybA[tid], rB = ybB[tid];          // tile 0 in regs
#pragma unroll 1
    for (int t = 0; t < NTILES; ++t) {
        tileA[tid] = rA;                          // write staged tile
        tileB[tid] = rB;
        __syncthreads();                          // tile t visible to all
        if (t + 1 < NTILES) {                     // issue next-tile loads early
            rA = ybA[(t + 1) * TPAIRS + tid];
            rB = ybB[(t + 1) * TPAIRS + tid];
        }
        const float4* tA = tileA + lane;
        const float4* tB = tileB + lane;
#pragma unroll
        for (int j = 0; j < 4; ++j) {
            float4 A = tA[j * 64];
            float4 Bv = tB[j * 64];
            PROCESS_PAIR(A, Bv)
        }
        __syncthreads();                          // all reads done before overwrite
    }

    // register-only cross-lane merge: 20 rounds of wave-max; winner lane
    // shifts its 4-deep list down (no LDS in the dependence chain).
    unsigned needmask = 0;
#pragma unroll
    for (int q = 0; q < RPW; ++q) {
        float h0 = bl[q][0], h1 = bl[q][1], h2 = bl[q][2], h3 = bl[q][3];
        int pops = 0;
        float sel = 0.0f;
        for (int r = 0; r < KSEL; ++r) {
            float mx = h0;
#pragma unroll
            for (int off = 32; off >= 1; off >>= 1) mx = fmaxf(mx, __shfl_xor(mx, off, 64));
            unsigned long long ball = __ballot(h0 == mx);
            int winner = (int)__ffsll(ball) - 1;  // first lane holding max (tie-safe)
            bool win = (lane == winner);
            h0 = win ? h1 : h0;
            h1 = win ? h2 : h1;
            h2 = win ? h3 : h2;
            h3 = win ? -3.0e38f : h3;
            pops += win ? 1 : 0;
            if (lane == r) sel = mx;
        }
        if (__ballot(pops >= MPL) != 0ULL) needmask |= (1u << q);
        if (lane < KSEL) dfeat[(size_t)(qbase + q) * KSEL + lane] = sel;
    }

    // exactness fallback: per flagged query, full per-lane top-20 rescan from
    // global (L2-hot), then 20-round register merge with 20-deep shift. Rare.
    if (needmask != 0) {
#pragma unroll
        for (int q = 0; q < RPW; ++q) {
            if (!(needmask & (1u << q))) continue;
            float a[KSEL];
#pragma unroll
            for (int j = 0; j < KSEL; ++j) a[j] = -3.0e38f;
#pragma unroll 1
            for (int t = 0; t < 32; ++t) {
                float4 dA0 = ybA[t * 128 + lane], dA1 = ybA[t * 128 + 64 + lane];
                float4 dB0 = ybB[t * 128 + lane], dB1 = ybB[t * 128 + 64 + lane];
                v2f t0 = {tx0[q], tx0[q]};
                v2f t1 = {tx1[q], tx1[q]};
                v2f t2 = {tx2[q], tx2[q]};
                v2f xp = {xxn[q], xxn[q]};
                v2f pd0 = fma2(t0, (v2f){dA0.x, dA0.y},
                          fma2(t1, (v2f){dA0.z, dA0.w},
                          fma2(t2, (v2f){dB0.x, dB0.y}, xp))) + (v2f){dB0.z, dB0.w};
                v2f pd1 = fma2(t0, (v2f){dA1.x, dA1.y},
                          fma2(t1, (v2f){dA1.z, dA1.w},
                          fma2(t2, (v2f){dB1.x, dB1.y}, xp))) + (v2f){dB1.z, dB1.w};
                float vv[4] = {pd0.x, pd0.y, pd1.x, pd1.y};
#pragma unroll
                for (int i = 0; i < 4; ++i) {
                    float v = vv[i];
#pragma unroll
                    for (int jj = KSEL - 1; jj >= 1; --jj) a[jj] = med3f(v, a[jj - 1], a[jj]);
                    a[0] = fmaxf(a[0], v);
                }
            }
            float sel2 = 0.0f;
            for (int r = 0; r < KSEL; ++r) {
                float mx = a[0];
#pragma unroll
                for (int off = 32; off >= 1; off >>= 1) mx = fmaxf(mx, __shfl_xor(mx, off, 64));
                unsigned long long ball = __ballot(a[0] == mx);
                int winner = (int)__ffsll(ball) - 1;
                bool win = (lane == winner);
#pragma unroll
                for (int jj = 0; jj < KSEL - 1; ++jj) a[jj] = win ? a[jj + 1] : a[jj];
                a[KSEL - 1] = win ? -3.0e38f : a[KSEL - 1];
                if (lane == r) sel2 = mx;
            }
            if (lane < KSEL) dfeat[(size_t)(qbase + q) * KSEL + lane] = sel2;
        }
    }
#undef PROCESS_PAIR
}

// ---------- kernel: fused MLP (bn1/relu -> GEMM2 -> bn2/relu -> W3 -> sigmoid) ----------
__global__ __launch_bounds__(256) void k_mlp(const float* __restrict__ dfeat,
                                             const float* __restrict__ W1,
                                             const float* __restrict__ g1,
                                             const float* __restrict__ be1,
                                             const float* __restrict__ mu1,
                                             const float* __restrict__ va1,
                                             const float* __restrict__ W2T,
                                             const float* __restrict__ g2,
                                             const float* __restrict__ be2,
                                             const float* __restrict__ mu2,
                                             const float* __restrict__ va2,
                                             const float* __restrict__ W3,
                                             float* __restrict__ out) {
    __shared__ float h1l[32 * 260];               // 33,280 B (stride 260: conflict-free)
    const int t = threadIdx.x;
    const int rowbase = blockIdx.x * 32;          // grid 512 -> all 16384 rows

    // phase-1 per-thread weights (o = t)
    float w[KSEL];
#pragma unroll
    for (int j = 0; j < KSEL; j += 4) {
        float4 q = *(const float4*)(W1 + t * KSEL + j);
        w[j] = q.x; w[j + 1] = q.y; w[j + 2] = q.z; w[j + 3] = q.w;
    }
    const float s1  = g1[t] * rsqrtf(va1[t] + 1e-5f);
    const float bc1 = be1[t] - mu1[t] * s1;

    // phase 1: h1[r][o] = relu(bn1(W1 . feat)), o = t; feat from global
    for (int r = 0; r < 32; ++r) {
        const float* dr = dfeat + (size_t)(rowbase + r) * KSEL;
        float dv[KSEL];
#pragma unroll
        for (int j = 0; j < KSEL; j += 4) {
            float4 q = *(const float4*)(dr + j);
            dv[j] = q.x; dv[j + 1] = q.y; dv[j + 2] = q.z; dv[j + 3] = q.w;
        }
        float acc0 = 0.f, acc1 = 0.f;
#pragma unroll
        for (int j = 0; j < KSEL; j += 2) {
            acc0 = fmaf(w[j], dv[j], acc0);
            acc1 = fmaf(w[j + 1], dv[j + 1], acc1);
        }
        h1l[r * 260 + t] = fmaxf(0.f, fmaf(s1, acc0 + acc1, bc1));
    }
    __syncthreads();                              // h1l ready

    // phase 2: GEMM 32 rows x 128 outs; thread = (og, rq)
    const int og = t & 15;
    const int rq = t >> 4;
    float acc[2][8];                              // [row][half*4+i]
#pragma unroll
    for (int r = 0; r < 2; ++r)
#pragma unroll
        for (int i = 0; i < 8; ++i) acc[r][i] = 0.f;

    for (int kq = 0; kq < 64; ++kq) {
        const int k = kq * 4;
        float4 hq[2];
#pragma unroll
        for (int rr = 0; rr < 2; ++rr)
            hq[rr] = *(const float4*)(&h1l[(rq * 2 + rr) * 260 + k]);
        float4 wq[8];                             // [kk] half0, [4+kk] half1
#pragma unroll
        for (int kk = 0; kk < 4; ++kk) {
            wq[kk]     = *(const float4*)(W2T + (k + kk) * 128 + og * 4);
            wq[4 + kk] = *(const float4*)(W2T + (k + kk) * 128 + 64 + og * 4);
        }
#pragma unroll
        for (int r = 0; r < 2; ++r) {
            const float* hh = (const float*)&hq[r];
#pragma unroll
            for (int kk = 0; kk < 4; ++kk) {
                const float hval = hh[kk];
                const float* w0 = (const float*)&wq[kk];
                const float* w1 = (const float*)&wq[4 + kk];
#pragma unroll
                for (int i = 0; i < 4; ++i) {
                    acc[r][i]     = fmaf(hval, w0[i], acc[r][i]);
                    acc[r][4 + i] = fmaf(hval, w1[i], acc[r][4 + i]);
                }
            }
        }
    }

    // epilogue: bn2 + relu + W3 weighting over 8 owned outs, reduce over og
    float s2v[8], b2v[8], w3v[8];
#pragma unroll
    for (int h = 0; h < 2; ++h)
#pragma unroll
        for (int i = 0; i < 4; ++i) {
            const int o = h * 64 + og * 4 + i;
            const float sv = g2[o] * rsqrtf(va2[o] + 1e-5f);
            s2v[h * 4 + i] = sv;
            b2v[h * 4 + i] = be2[o] - mu2[o] * sv;
            w3v[h * 4 + i] = W3[o];
        }
#pragma unroll
    for (int r = 0; r < 2; ++r) {
        float c = 0.f;
#pragma unroll
        for (int i = 0; i < 8; ++i) {
            float h2 = fmaxf(0.f, fmaf(s2v[i], acc[r][i], b2v[i]));
            c = fmaf(w3v[i], h2, c);
        }
#pragma unroll
        for (int off = 8; off >= 1; off >>= 1) c += __shfl_xor(c, off, 64);
        if (og == 0) {
            out[rowbase + rq * 2 + r] = 1.0f / (1.0f + expf(-c));
        }
    }
}

extern "C" void kernel_launch(void* const* d_in, const int* in_sizes, int n_in,
                              void* d_out, int out_size, void* d_ws, size_t ws_size,
                              hipStream_t stream) {
    const float* x   = (const float*)d_in[0];
    const float* y   = (const float*)d_in[1];
    const float* W1  = (const float*)d_in[2];
    const float* g1  = (const float*)d_in[3];
    const float* be1 = (const float*)d_in[4];
    const float* mu1 = (const float*)d_in[5];
    const float* va1 = (const float*)d_in[6];
    const float* W2  = (const float*)d_in[7];
    const float* g2  = (const float*)d_in[8];
    const float* be2 = (const float*)d_in[9];
    const float* mu2 = (const float*)d_in[10];
    const float* va2 = (const float*)d_in[11];
    const float* W3  = (const float*)d_in[12];
    float* out = (float*)d_out;

    char* ws = (char*)d_ws;
    float4* ysp  = (float4*)(ws);                                   // 262,144 B
    float* dfeat = (float*)(ws + 262144);                           // 1,310,720 B
    float* w2t   = (float*)(ws + 262144 + 1310720);                 // 131,072 B

    k_prep<<<160, 256, 0, stream>>>(y, W2, ysp, w2t);
    k_knn <<<1024, 256, 0, stream>>>(x, ysp, dfeat);
    k_mlp <<<512, 256, 0, stream>>>(dfeat, W1, g1, be1, mu1, va1,
                                    w2t, g2, be2, mu2, va2, W3, out);
}